// Round 3
// baseline (177.820 us; speedup 1.0000x reference)
//
#include <hip/hip_runtime.h>

#define NBATCH 128
#define NANCH  8732
#define NCLS   21
#define GRPS   2183                    // 8732 / 4 exactly
#define SUBS   9                       // ceil(2183/256) blocks per batch

// ws: float4 partial[NBATCH * SUBS] -> 128*9*16 = 18432 bytes
// partial = { loc_sum, con_sum_all, con_sum_pos, pos_count }

// ---------------------------------------------------------------- helpers
__device__ __forceinline__ float waveReduceF(float v) {
    #pragma unroll
    for (int o = 32; o > 0; o >>= 1) v += __shfl_down(v, o, 64);
    return v;
}
__device__ __forceinline__ unsigned waveReduceU(unsigned v) {
    #pragma unroll
    for (int o = 32; o > 0; o >>= 1) v += __shfl_down(v, o, 64);
    return v;
}

// cross entropy for the cold mining path only
__device__ __forceinline__ float con_from_row(const float* __restrict__ row, int lbl) {
    float m = row[0];
    #pragma unroll
    for (int c = 1; c < NCLS; ++c) m = fmaxf(m, row[c]);
    float s = 0.f;
    #pragma unroll
    for (int c = 0; c < NCLS; ++c) s += __expf(row[c] - m);
    return m + __logf(s) - row[lbl];
}

// ---------------------------------------------------------------- kernel 1
// Max-stream probe: ONE thread per 4-anchor group. 4 rows * 84B = 336B =
// 21 float4, 16B-aligned (group base byte = group*336, 336%16==0). Each lane
// bursts 30 independent aligned 16B loads (21 cls + 4 lo + 4 ll + 1 int4
// labels) with zero dependent chains and zero barriers, then computes.
// Target logit selected via cndmask in the max pass (no runtime-indexed
// array -> no scratch). grid = 9 x 128 = 1152 blocks, 12 waves/CU resident
// at launch_bounds(256,3): ~370 KB outstanding per CU.
__global__ __launch_bounds__(256, 3) void anchor_kernel(
    const float*  __restrict__ loc_out,   // [B,A,4]
    const float*  __restrict__ cls_out,   // [B,A,C]
    const float*  __restrict__ loc_lab,   // [B,A,4]
    const int*    __restrict__ labels,    // [B,A]
    float4* __restrict__ partial)         // [NBATCH*SUBS]
{
    const int b   = blockIdx.y;
    const int s   = blockIdx.x;
    const int tid = threadIdx.x;
    const int g   = s * 256 + tid;        // group of 4 anchors

    float loc_s = 0.f, all_s = 0.f, pos_s = 0.f;
    unsigned pc = 0;

    if (g < GRPS) {
        const size_t ba0 = (size_t)b * NANCH + (size_t)g * 4;   // %4 == 0

        // ---- issue the whole independent load burst ----
        const int4 lbl4 = *(const int4*)(labels + ba0);
        const float4* __restrict__ cp = (const float4*)(cls_out + ba0 * NCLS);
        float f[84];
        #pragma unroll
        for (int i = 0; i < 21; ++i) {
            const float4 v = cp[i];
            f[4*i+0] = v.x; f[4*i+1] = v.y; f[4*i+2] = v.z; f[4*i+3] = v.w;
        }
        float4 lo[4], ll[4];
        #pragma unroll
        for (int j = 0; j < 4; ++j) {
            lo[j] = ((const float4*)loc_out)[ba0 + j];
            ll[j] = ((const float4*)loc_lab)[ba0 + j];
        }
        int lbls[4] = { lbl4.x, lbl4.y, lbl4.z, lbl4.w };

        // ---- per-anchor CE + masked SmoothL1 (all static indexing) ----
        #pragma unroll
        for (int j = 0; j < 4; ++j) {
            const int lbl = lbls[j];
            float m   = f[21*j];
            float tgt = f[21*j];          // lbl==0 case
            #pragma unroll
            for (int cc = 1; cc < NCLS; ++cc) {
                const float v = f[21*j + cc];
                m = fmaxf(m, v);
                tgt = (cc == lbl) ? v : tgt;
            }
            float sum = 0.f;
            #pragma unroll
            for (int cc = 0; cc < NCLS; ++cc)
                sum += __expf(f[21*j + cc] - m);

            const float con = m + __logf(sum) - tgt;
            all_s += con;
            if (lbl > 0) {
                pos_s += con;
                pc++;
                const float d0 = lo[j].x - ll[j].x, d1 = lo[j].y - ll[j].y,
                            d2 = lo[j].z - ll[j].z, d3 = lo[j].w - ll[j].w;
                const float a0 = fabsf(d0), a1 = fabsf(d1),
                            a2 = fabsf(d2), a3 = fabsf(d3);
                loc_s += ((a0 < 1.f) ? 0.5f * d0 * d0 : (a0 - 0.5f))
                       + ((a1 < 1.f) ? 0.5f * d1 * d1 : (a1 - 0.5f))
                       + ((a2 < 1.f) ? 0.5f * d2 * d2 : (a2 - 0.5f))
                       + ((a3 < 1.f) ? 0.5f * d3 * d3 : (a3 - 0.5f));
            }
        }
    }

    // block reduce: wave shuffle then tiny LDS (4 waves)
    loc_s = waveReduceF(loc_s);
    all_s = waveReduceF(all_s);
    pos_s = waveReduceF(pos_s);
    pc    = waveReduceU(pc);

    __shared__ float sL[4], sA[4], sP[4];
    __shared__ unsigned sC[4];
    const int w = tid >> 6, lane = tid & 63;
    if (lane == 0) { sL[w] = loc_s; sA[w] = all_s; sP[w] = pos_s; sC[w] = pc; }
    __syncthreads();
    if (tid == 0) {
        float L = sL[0] + sL[1] + sL[2] + sL[3];
        float S = sA[0] + sA[1] + sA[2] + sA[3];
        float P = sP[0] + sP[1] + sP[2] + sP[3];
        unsigned C = sC[0] + sC[1] + sC[2] + sC[3];
        partial[b * SUBS + s] = make_float4(L, S, P, (float)C);
    }
}

// ---------------------------------------------------------------- kernel 2
// Single block. Threads 0..127 each own a batch: reduce the 9 partials,
// apply mining formula (hot path: all-ones neg_mask), block-reduce the mean.
__global__ __launch_bounds__(256) void finalize_kernel(
    const float* __restrict__ cls_out,
    const int*   __restrict__ labels,
    const float4* __restrict__ partial,
    float* __restrict__ out)
{
    const int tid = threadIdx.x;

    __shared__ float sLoc[NBATCH], sPos[NBATCH], sCnt[NBATCH], sConl[NBATCH];
    __shared__ unsigned sK[NBATCH];
    __shared__ unsigned nflag;
    if (tid == 0) nflag = 0;
    __syncthreads();

    if (tid < NBATCH) {
        float loc = 0.f, all = 0.f, pos = 0.f, cnt = 0.f;
        #pragma unroll
        for (int c = 0; c < SUBS; ++c) {
            float4 p = partial[tid * SUBS + c];
            loc += p.x; all += p.y; pos += p.z; cnt += p.w;
        }
        unsigned k = 3u * (unsigned)cnt;
        if (k > NANCH) k = NANCH;
        if (k == 0u) k = 3u;
        sLoc[tid] = loc; sPos[tid] = pos; sCnt[tid] = cnt;
        sConl[tid] = all + pos;          // hot path: neg_mask all-ones
        if (k < NANCH) { sK[tid] = k; atomicAdd(&nflag, 1u); }
        else sK[tid] = 0u;
    }
    __syncthreads();

    if (nflag) {
        // cold general path: exact top-k of con_neg per flagged batch
        __shared__ float    rF[256];
        __shared__ unsigned rU[256];
        for (int b2 = 0; b2 < NBATCH; ++b2) {
            unsigned k = sK[b2];
            if (!k) continue;

            auto count_gt = [&](float t) -> unsigned {
                unsigned cc = 0;
                for (int an = tid; an < NANCH; an += 256) {
                    size_t ba = (size_t)b2 * NANCH + an;
                    int lbl = labels[ba];
                    if (lbl > 0) continue;
                    float con = con_from_row(cls_out + ba * NCLS, lbl);
                    if (con > t) cc++;
                }
                rU[tid] = cc; __syncthreads();
                for (int o = 128; o > 0; o >>= 1) {
                    if (tid < o) rU[tid] += rU[tid + o];
                    __syncthreads();
                }
                unsigned r = rU[0]; __syncthreads();
                return r;
            };

            unsigned cpos = count_gt(0.0f);
            float negpart = 0.f;

            if (k <= cpos) {
                unsigned lo = 0u, hi = 0x7F800000u;
                while (hi - lo > 1u) {
                    unsigned mid = lo + (hi - lo) / 2u;
                    unsigned cc = count_gt(__uint_as_float(mid));
                    if (cc >= k) lo = mid; else hi = mid;
                }
                float v = __uint_as_float(hi);   // k-th largest value
                float ss = 0.f; unsigned c1 = 0;
                for (int an = tid; an < NANCH; an += 256) {
                    size_t ba = (size_t)b2 * NANCH + an;
                    int lbl = labels[ba];
                    if (lbl > 0) continue;
                    float con = con_from_row(cls_out + ba * NCLS, lbl);
                    if (con > v) { ss += con; c1++; }
                }
                rF[tid] = ss; rU[tid] = c1; __syncthreads();
                for (int o = 128; o > 0; o >>= 1) {
                    if (tid < o) { rF[tid] += rF[tid + o]; rU[tid] += rU[tid + o]; }
                    __syncthreads();
                }
                negpart = rF[0] + (float)(k - rU[0]) * v;
                __syncthreads();
            } else {
                if (tid == 0) {
                    float np = 0.f;
                    unsigned mrem = k - cpos;
                    for (int an = 0; an < NANCH; ++an) {
                        size_t ba = (size_t)b2 * NANCH + an;
                        int lbl = labels[ba];
                        float con = con_from_row(cls_out + ba * NCLS, lbl);
                        float cneg = (lbl > 0) ? 0.f : con;
                        if (cneg > 0.f) np += con;
                        else if (mrem > 0u) { np += con; mrem--; }
                    }
                    rF[0] = np;
                }
                __syncthreads();
                negpart = rF[0];
                __syncthreads();
            }

            if (tid == 0) sConl[b2] = sPos[b2] + negpart;
            __syncthreads();
        }
    }

    // final mean over batches
    float t = 0.f;
    if (tid < NBATCH) {
        float denom = (sCnt[tid] != 0.f) ? sCnt[tid] : 1.f;
        t = (sLoc[tid] + sConl[tid]) / denom;
    }
    t = waveReduceF(t);
    __shared__ float sW[4];
    const int w = tid >> 6, lane = tid & 63;
    if (lane == 0) sW[w] = t;
    __syncthreads();
    if (tid == 0) out[0] = (sW[0] + sW[1] + sW[2] + sW[3]) * (1.f / NBATCH);
}

// ---------------------------------------------------------------- launch
extern "C" void kernel_launch(void* const* d_in, const int* in_sizes, int n_in,
                              void* d_out, int out_size, void* d_ws, size_t ws_size,
                              hipStream_t stream) {
    const float* loc_out = (const float*)d_in[0];
    const float* cls_out = (const float*)d_in[1];
    const float* loc_lab = (const float*)d_in[2];
    const int*   labels  = (const int*)d_in[3];
    float* out = (float*)d_out;
    float4* partial = (float4*)d_ws;   // 128*9*16 = 18432 B of ws

    dim3 grid(SUBS, NBATCH);
    anchor_kernel<<<grid, 256, 0, stream>>>(loc_out, cls_out, loc_lab, labels, partial);
    finalize_kernel<<<1, 256, 0, stream>>>(cls_out, labels, partial, out);
}

// Round 4
// 176.323 us; speedup vs baseline: 1.0085x; 1.0085x over previous
//
#include <hip/hip_runtime.h>

#define NBATCH 128
#define NANCH  8732
#define NCLS   21
#define SUBSX  8                       // blocks per batch
#define STEP   (SUBSX * 256)           // 2048 anchors per stage
// stages: 0..3 always valid (3*2048+2047 = 8191 < 8732), stage 4 iff a0 < 540

// ws: float4 partial[NBATCH * SUBSX] -> 128*8*16 = 16384 bytes
// partial = { loc_sum, con_sum_all, con_sum_pos, pos_count }

// ---------------------------------------------------------------- helpers
__device__ __forceinline__ float waveReduceF(float v) {
    #pragma unroll
    for (int o = 32; o > 0; o >>= 1) v += __shfl_down(v, o, 64);
    return v;
}
__device__ __forceinline__ unsigned waveReduceU(unsigned v) {
    #pragma unroll
    for (int o = 32; o > 0; o >>= 1) v += __shfl_down(v, o, 64);
    return v;
}

// cross entropy for the cold mining path only
__device__ __forceinline__ float con_from_row(const float* __restrict__ row, int lbl) {
    float m = row[0];
    #pragma unroll
    for (int c = 1; c < NCLS; ++c) m = fmaxf(m, row[c]);
    float s = 0.f;
    #pragma unroll
    for (int c = 0; c < NCLS; ++c) s += __expf(row[c] - m);
    return m + __logf(s) - row[lbl];
}

// ---------------------------------------------------------------- kernel 1
// Software-pipelined grid-stride: 1024 blocks (8 per batch) x 256 threads,
// each thread walks 5 anchors at stride 2048. Two register buffers (named
// structs -> static indexing, no scratch) alternate: while computing buffer
// X, buffer Y's 9 independent loads are in flight. The memory queue never
// drains -- unlike all prior variants, which drained vmcnt to 0 before each
// compute phase. launch_bounds(256,4): VGPR cap 128 (need ~90), 16 waves/CU.
struct Abuf {
    float4 r0, r1, r2, r3, r4;   // 20 logits
    float  r5;                   // logit 20
    float4 lo, ll;               // loc_out / loc_label
    int    lbl;
};

__device__ __forceinline__ void load_anchor(
    Abuf& bf, const float* __restrict__ cls_out,
    const float4* __restrict__ loc_out, const float4* __restrict__ loc_lab,
    const int* __restrict__ labels, size_t ba, bool valid)
{
    if (valid) {
        const float* __restrict__ row = cls_out + ba * NCLS;
        bf.lbl = labels[ba];
        bf.r0 = *(const float4*)(row +  0);
        bf.r1 = *(const float4*)(row +  4);
        bf.r2 = *(const float4*)(row +  8);
        bf.r3 = *(const float4*)(row + 12);
        bf.r4 = *(const float4*)(row + 16);
        bf.r5 = row[20];
        bf.lo = loc_out[ba];
        bf.ll = loc_lab[ba];
    } else {
        bf.lbl = 0;
    }
}

__device__ __forceinline__ void compute_anchor(
    const Abuf& bf, bool valid,
    float& loc_s, float& all_s, float& pos_s, unsigned& pc)
{
    if (!valid) return;
    const int lbl = bf.lbl;
    float m   = bf.r0.x;
    float tgt = bf.r0.x;               // lbl==0 default
    // max + target select in one static pass over the 21 components
    #define MAXSEL(i, comp) { const float v_ = (comp); m = fmaxf(m, v_); \
                              tgt = (lbl == (i)) ? v_ : tgt; }
    MAXSEL( 1, bf.r0.y) MAXSEL( 2, bf.r0.z) MAXSEL( 3, bf.r0.w)
    MAXSEL( 4, bf.r1.x) MAXSEL( 5, bf.r1.y) MAXSEL( 6, bf.r1.z) MAXSEL( 7, bf.r1.w)
    MAXSEL( 8, bf.r2.x) MAXSEL( 9, bf.r2.y) MAXSEL(10, bf.r2.z) MAXSEL(11, bf.r2.w)
    MAXSEL(12, bf.r3.x) MAXSEL(13, bf.r3.y) MAXSEL(14, bf.r3.z) MAXSEL(15, bf.r3.w)
    MAXSEL(16, bf.r4.x) MAXSEL(17, bf.r4.y) MAXSEL(18, bf.r4.z) MAXSEL(19, bf.r4.w)
    MAXSEL(20, bf.r5)
    #undef MAXSEL

    float sum = __expf(bf.r0.x - m) + __expf(bf.r0.y - m)
              + __expf(bf.r0.z - m) + __expf(bf.r0.w - m)
              + __expf(bf.r1.x - m) + __expf(bf.r1.y - m)
              + __expf(bf.r1.z - m) + __expf(bf.r1.w - m)
              + __expf(bf.r2.x - m) + __expf(bf.r2.y - m)
              + __expf(bf.r2.z - m) + __expf(bf.r2.w - m)
              + __expf(bf.r3.x - m) + __expf(bf.r3.y - m)
              + __expf(bf.r3.z - m) + __expf(bf.r3.w - m)
              + __expf(bf.r4.x - m) + __expf(bf.r4.y - m)
              + __expf(bf.r4.z - m) + __expf(bf.r4.w - m)
              + __expf(bf.r5 - m);

    const float con = m + __logf(sum) - tgt;
    all_s += con;
    if (lbl > 0) {
        pos_s += con;
        pc++;
        const float d0 = bf.lo.x - bf.ll.x, d1 = bf.lo.y - bf.ll.y,
                    d2 = bf.lo.z - bf.ll.z, d3 = bf.lo.w - bf.ll.w;
        const float a0 = fabsf(d0), a1 = fabsf(d1),
                    a2 = fabsf(d2), a3 = fabsf(d3);
        loc_s += ((a0 < 1.f) ? 0.5f * d0 * d0 : (a0 - 0.5f))
               + ((a1 < 1.f) ? 0.5f * d1 * d1 : (a1 - 0.5f))
               + ((a2 < 1.f) ? 0.5f * d2 * d2 : (a2 - 0.5f))
               + ((a3 < 1.f) ? 0.5f * d3 * d3 : (a3 - 0.5f));
    }
}

__global__ __launch_bounds__(256, 4) void anchor_kernel(
    const float*  __restrict__ loc_out,   // [B,A,4]
    const float*  __restrict__ cls_out,   // [B,A,C]
    const float*  __restrict__ loc_lab,   // [B,A,4]
    const int*    __restrict__ labels,    // [B,A]
    float4* __restrict__ partial)         // [NBATCH*SUBSX]
{
    const int b   = blockIdx.y;
    const int s   = blockIdx.x;
    const int tid = threadIdx.x;
    const int a0  = s * 256 + tid;        // in [0, 2048)
    const size_t base = (size_t)b * NANCH;

    const float4* lo_p = (const float4*)loc_out;
    const float4* ll_p = (const float4*)loc_lab;

    float loc_s = 0.f, all_s = 0.f, pos_s = 0.f;
    unsigned pc = 0;

    Abuf A, B;
    const bool v4 = a0 < (NANCH - 4 * STEP);   // a0 < 540

    // pipeline: L0(A) L1(B) C0(A) L2(A) C1(B) L3(B) C2(A) L4(A) C3(B) C4(A)
    load_anchor(A, cls_out, lo_p, ll_p, labels, base + a0,            true);
    load_anchor(B, cls_out, lo_p, ll_p, labels, base + a0 + 1 * STEP, true);
    compute_anchor(A, true, loc_s, all_s, pos_s, pc);
    load_anchor(A, cls_out, lo_p, ll_p, labels, base + a0 + 2 * STEP, true);
    compute_anchor(B, true, loc_s, all_s, pos_s, pc);
    load_anchor(B, cls_out, lo_p, ll_p, labels, base + a0 + 3 * STEP, true);
    compute_anchor(A, true, loc_s, all_s, pos_s, pc);
    load_anchor(A, cls_out, lo_p, ll_p, labels, base + a0 + 4 * STEP, v4);
    compute_anchor(B, true, loc_s, all_s, pos_s, pc);
    compute_anchor(A, v4,   loc_s, all_s, pos_s, pc);

    // block reduce: wave shuffle then tiny LDS (4 waves)
    loc_s = waveReduceF(loc_s);
    all_s = waveReduceF(all_s);
    pos_s = waveReduceF(pos_s);
    pc    = waveReduceU(pc);

    __shared__ float sL[4], sA[4], sP[4];
    __shared__ unsigned sC[4];
    const int w = tid >> 6, lane = tid & 63;
    if (lane == 0) { sL[w] = loc_s; sA[w] = all_s; sP[w] = pos_s; sC[w] = pc; }
    __syncthreads();
    if (tid == 0) {
        float L = sL[0] + sL[1] + sL[2] + sL[3];
        float S = sA[0] + sA[1] + sA[2] + sA[3];
        float P = sP[0] + sP[1] + sP[2] + sP[3];
        unsigned C = sC[0] + sC[1] + sC[2] + sC[3];
        partial[b * SUBSX + s] = make_float4(L, S, P, (float)C);
    }
}

// ---------------------------------------------------------------- kernel 2
// Single block. Threads 0..127 each own a batch: reduce the 8 partials,
// apply mining formula (hot path: all-ones neg_mask), block-reduce the mean.
__global__ __launch_bounds__(256) void finalize_kernel(
    const float* __restrict__ cls_out,
    const int*   __restrict__ labels,
    const float4* __restrict__ partial,
    float* __restrict__ out)
{
    const int tid = threadIdx.x;

    __shared__ float sLoc[NBATCH], sPos[NBATCH], sCnt[NBATCH], sConl[NBATCH];
    __shared__ unsigned sK[NBATCH];
    __shared__ unsigned nflag;
    if (tid == 0) nflag = 0;
    __syncthreads();

    if (tid < NBATCH) {
        float loc = 0.f, all = 0.f, pos = 0.f, cnt = 0.f;
        #pragma unroll
        for (int c = 0; c < SUBSX; ++c) {
            float4 p = partial[tid * SUBSX + c];
            loc += p.x; all += p.y; pos += p.z; cnt += p.w;
        }
        unsigned k = 3u * (unsigned)cnt;
        if (k > NANCH) k = NANCH;
        if (k == 0u) k = 3u;
        sLoc[tid] = loc; sPos[tid] = pos; sCnt[tid] = cnt;
        sConl[tid] = all + pos;          // hot path: neg_mask all-ones
        if (k < NANCH) { sK[tid] = k; atomicAdd(&nflag, 1u); }
        else sK[tid] = 0u;
    }
    __syncthreads();

    if (nflag) {
        // cold general path: exact top-k of con_neg per flagged batch
        __shared__ float    rF[256];
        __shared__ unsigned rU[256];
        for (int b2 = 0; b2 < NBATCH; ++b2) {
            unsigned k = sK[b2];
            if (!k) continue;

            auto count_gt = [&](float t) -> unsigned {
                unsigned cc = 0;
                for (int an = tid; an < NANCH; an += 256) {
                    size_t ba = (size_t)b2 * NANCH + an;
                    int lbl = labels[ba];
                    if (lbl > 0) continue;
                    float con = con_from_row(cls_out + ba * NCLS, lbl);
                    if (con > t) cc++;
                }
                rU[tid] = cc; __syncthreads();
                for (int o = 128; o > 0; o >>= 1) {
                    if (tid < o) rU[tid] += rU[tid + o];
                    __syncthreads();
                }
                unsigned r = rU[0]; __syncthreads();
                return r;
            };

            unsigned cpos = count_gt(0.0f);
            float negpart = 0.f;

            if (k <= cpos) {
                unsigned lo = 0u, hi = 0x7F800000u;
                while (hi - lo > 1u) {
                    unsigned mid = lo + (hi - lo) / 2u;
                    unsigned cc = count_gt(__uint_as_float(mid));
                    if (cc >= k) lo = mid; else hi = mid;
                }
                float v = __uint_as_float(hi);   // k-th largest value
                float ss = 0.f; unsigned c1 = 0;
                for (int an = tid; an < NANCH; an += 256) {
                    size_t ba = (size_t)b2 * NANCH + an;
                    int lbl = labels[ba];
                    if (lbl > 0) continue;
                    float con = con_from_row(cls_out + ba * NCLS, lbl);
                    if (con > v) { ss += con; c1++; }
                }
                rF[tid] = ss; rU[tid] = c1; __syncthreads();
                for (int o = 128; o > 0; o >>= 1) {
                    if (tid < o) { rF[tid] += rF[tid + o]; rU[tid] += rU[tid + o]; }
                    __syncthreads();
                }
                negpart = rF[0] + (float)(k - rU[0]) * v;
                __syncthreads();
            } else {
                if (tid == 0) {
                    float np = 0.f;
                    unsigned mrem = k - cpos;
                    for (int an = 0; an < NANCH; ++an) {
                        size_t ba = (size_t)b2 * NANCH + an;
                        int lbl = labels[ba];
                        float con = con_from_row(cls_out + ba * NCLS, lbl);
                        float cneg = (lbl > 0) ? 0.f : con;
                        if (cneg > 0.f) np += con;
                        else if (mrem > 0u) { np += con; mrem--; }
                    }
                    rF[0] = np;
                }
                __syncthreads();
                negpart = rF[0];
                __syncthreads();
            }

            if (tid == 0) sConl[b2] = sPos[b2] + negpart;
            __syncthreads();
        }
    }

    // final mean over batches
    float t = 0.f;
    if (tid < NBATCH) {
        float denom = (sCnt[tid] != 0.f) ? sCnt[tid] : 1.f;
        t = (sLoc[tid] + sConl[tid]) / denom;
    }
    t = waveReduceF(t);
    __shared__ float sW[4];
    const int w = tid >> 6, lane = tid & 63;
    if (lane == 0) sW[w] = t;
    __syncthreads();
    if (tid == 0) out[0] = (sW[0] + sW[1] + sW[2] + sW[3]) * (1.f / NBATCH);
}

// ---------------------------------------------------------------- launch
extern "C" void kernel_launch(void* const* d_in, const int* in_sizes, int n_in,
                              void* d_out, int out_size, void* d_ws, size_t ws_size,
                              hipStream_t stream) {
    const float* loc_out = (const float*)d_in[0];
    const float* cls_out = (const float*)d_in[1];
    const float* loc_lab = (const float*)d_in[2];
    const int*   labels  = (const int*)d_in[3];
    float* out = (float*)d_out;
    float4* partial = (float4*)d_ws;   // 128*8*16 = 16384 B of ws

    dim3 grid(SUBSX, NBATCH);
    anchor_kernel<<<grid, 256, 0, stream>>>(loc_out, cls_out, loc_lab, labels, partial);
    finalize_kernel<<<1, 256, 0, stream>>>(cls_out, labels, partial, out);
}